// Round 17
// baseline (152.804 us; speedup 1.0000x reference)
//
#include <hip/hip_runtime.h>

typedef __attribute__((ext_vector_type(8))) _Float16 half8;
typedef __attribute__((ext_vector_type(2))) __fp16 fp16x2;
typedef __attribute__((ext_vector_type(4))) float f32x4;

#define XDIM 8192
#define XOUT 8191
#define TPW 16                     // tiles (of 16 positions) per wave
#define NTILES (1024 * 512)        // 512 tiles per row, 1024 rows
#define NBLOCKS (NTILES / TPW / 4) // 4 waves per block

// 8 halves: elems 0-3 -> k = kb+j in k-block 0..15, elems 4-7 -> k-block 16..31
// (layout verified on HW: r11/r12 absmax 0.0)
union H8 {
    fp16x2 p[4];
    half8 v;
};

#define MFMA32(A, B, C) __builtin_amdgcn_mfma_f32_16x16x32_f16((A), (B), (C), 0, 0, 0)

__global__ __attribute__((amdgpu_flat_work_group_size(256, 256)))
void cnn_mfma_kernel(
    const float* __restrict__ rho, const float* __restrict__ w0,
    const float* __restrict__ b0, const float* __restrict__ Wh,
    const float* __restrict__ bh, const float* __restrict__ Wl,
    const float* __restrict__ bl, float* __restrict__ out) {
    const int lane = threadIdx.x & 63;
    const int lm = lane & 15;          // A-row (out ch) / B-col (position) / D-col
    const int kb = (lane >> 4) * 4;    // k-base within block / D row-base
    const bool biaslane = (kb == 12);  // this group's elem 3 is the k=15 bias slot

    // ---- per-layer constant A fragments:
    //      A1 = [Whi | Whi], A2 = [Wlo | 0]; bias folded into k=15 column
    //      (A[o][15] = bias_hi/lo, B[k=15] forced to 1.0 each layer).
    half8 A1_0, A1_1, A1_2, A1_3, A1_4;
    half8 A2_0, A2_1, A2_2, A2_3, A2_4;
#define LOADA(L, A1F, A2F)                                                        \
    {                                                                             \
        float _w0 = (lm < 15) ? Wh[(L)*225 + lm*15 + kb + 0] : 0.f;               \
        float _w1 = (lm < 15) ? Wh[(L)*225 + lm*15 + kb + 1] : 0.f;               \
        float _w2 = (lm < 15) ? Wh[(L)*225 + lm*15 + kb + 2] : 0.f;               \
        float _w3 = (lm < 15) ? (biaslane ? bh[(L)*15 + lm]                       \
                                          : Wh[(L)*225 + lm*15 + kb + 3]) : 0.f;  \
        fp16x2 _h01 = __builtin_amdgcn_cvt_pkrtz(_w0, _w1);                       \
        fp16x2 _h23 = __builtin_amdgcn_cvt_pkrtz(_w2, _w3);                       \
        const float _e0 = fmaf(-1.0f, (float)_h01.x, _w0);                        \
        const float _e1 = fmaf(-1.0f, (float)_h01.y, _w1);                        \
        const float _e2 = fmaf(-1.0f, (float)_h23.x, _w2);                        \
        const float _e3 = fmaf(-1.0f, (float)_h23.y, _w3);                        \
        fp16x2 _l01 = __builtin_amdgcn_cvt_pkrtz(_e0, _e1);                       \
        fp16x2 _l23 = __builtin_amdgcn_cvt_pkrtz(_e2, _e3);                       \
        H8 _u1, _u2;                                                              \
        _u1.p[0] = _h01; _u1.p[1] = _h23; _u1.p[2] = _h01; _u1.p[3] = _h23;       \
        fp16x2 _z = __builtin_amdgcn_cvt_pkrtz(0.f, 0.f);                         \
        _u2.p[0] = _l01; _u2.p[1] = _l23; _u2.p[2] = _z;   _u2.p[3] = _z;         \
        A1F = _u1.v;                                                              \
        A2F = _u2.v;                                                              \
    }
    LOADA(0, A1_0, A2_0)
    LOADA(1, A1_1, A2_1)
    LOADA(2, A1_2, A2_2)
    LOADA(3, A1_3, A2_3)
    LOADA(4, A1_4, A2_4)
#undef LOADA

    // first-conv weights for this lane's 4 channels (kb..kb+3); ch 15 -> 0
    float fw0_0 = (kb + 0 < 15) ? w0[2*(kb+0)]   : 0.f;
    float fw1_0 = (kb + 0 < 15) ? w0[2*(kb+0)+1] : 0.f;
    float fb_0  = (kb + 0 < 15) ? b0[kb+0]       : 0.f;
    float fw0_1 = (kb + 1 < 15) ? w0[2*(kb+1)]   : 0.f;
    float fw1_1 = (kb + 1 < 15) ? w0[2*(kb+1)+1] : 0.f;
    float fb_1  = (kb + 1 < 15) ? b0[kb+1]       : 0.f;
    float fw0_2 = (kb + 2 < 15) ? w0[2*(kb+2)]   : 0.f;
    float fw1_2 = (kb + 2 < 15) ? w0[2*(kb+2)+1] : 0.f;
    float fb_2  = (kb + 2 < 15) ? b0[kb+2]       : 0.f;
    float fw0_3 = (kb + 3 < 15) ? w0[2*(kb+3)]   : 0.f;
    float fw1_3 = (kb + 3 < 15) ? w0[2*(kb+3)+1] : 0.f;
    float fb_3  = (kb + 3 < 15) ? b0[kb+3]       : 0.f;

    float wl0 = (kb + 0 < 15) ? Wl[kb + 0] : 0.f;
    float wl1 = (kb + 1 < 15) ? Wl[kb + 1] : 0.f;
    float wl2 = (kb + 2 < 15) ? Wl[kb + 2] : 0.f;
    float wl3 = (kb + 3 < 15) ? Wl[kb + 3] : 0.f;
    const float bl0 = bl[0];

    // ---- each wave owns 16 consecutive tiles of one row ----
    const int wid = blockIdx.x * 4 + (threadIdx.x >> 6);   // 0..32767
    const int brow = wid >> 5;                             // 32 waves per row
    const int xb = ((wid & 31) << 8) + lm;                 // + t*16, t in [0,16)
    const float* rrow = rho + (size_t)brow * XDIM;
    float* orow = out + (size_t)brow * XOUT;

#pragma unroll 2
    for (int t = 0; t < TPW; ++t) {
        // PIN: empty asm "rewrites" every weight register each iteration, so
        // the allocator CANNOT re-load/remat them per tile (the r9-r16 failure:
        // budget-driven remat kept VGPR=52 and re-fetched weights every tile).
        asm volatile("" :
            "+v"(A1_0), "+v"(A1_1), "+v"(A1_2), "+v"(A1_3), "+v"(A1_4),
            "+v"(A2_0), "+v"(A2_1), "+v"(A2_2), "+v"(A2_3), "+v"(A2_4));
        asm volatile("" :
            "+v"(fw0_0), "+v"(fw1_0), "+v"(fb_0), "+v"(fw0_1), "+v"(fw1_1),
            "+v"(fb_1), "+v"(fw0_2), "+v"(fw1_2), "+v"(fb_2), "+v"(fw0_3),
            "+v"(fw1_3), "+v"(fb_3), "+v"(wl0), "+v"(wl1), "+v"(wl2), "+v"(wl3));

        const int x = xb + t * 16;                 // <= 8191
        const float r0 = rrow[x];
        const float r1 = rrow[(x < XDIM - 1) ? x + 1 : XDIM - 1];

        // first conv (k=2) + relu; bias-slot lane's elem3 forced to 1.0
        float h0 = fmaxf(fmaf(fw0_0, r0, fmaf(fw1_0, r1, fb_0)), 0.f);
        float h1 = fmaxf(fmaf(fw0_1, r0, fmaf(fw1_1, r1, fb_1)), 0.f);
        float h2 = fmaxf(fmaf(fw0_2, r0, fmaf(fw1_2, r1, fb_2)), 0.f);
        float h3 = biaslane ? 1.0f
                            : fmaxf(fmaf(fw0_3, r0, fmaf(fw1_3, r1, fb_3)), 0.f);

        // Per layer: B = [hhi|hlo] (natural order); D = A1*B + A2*B
        //          = (Whi+Wlo)(hhi) + Whi(hlo) + bias (via k=15 slot).
#define HLAYER(A1F, A2F)                                             \
        {                                                            \
            H8 _b;                                                   \
            _b.p[0] = __builtin_amdgcn_cvt_pkrtz(h0, h1);            \
            _b.p[1] = __builtin_amdgcn_cvt_pkrtz(h2, h3);            \
            const float _e0 = fmaf(-1.0f, (float)_b.p[0].x, h0);     \
            const float _e1 = fmaf(-1.0f, (float)_b.p[0].y, h1);     \
            const float _e2 = fmaf(-1.0f, (float)_b.p[1].x, h2);     \
            const float _e3 = fmaf(-1.0f, (float)_b.p[1].y, h3);     \
            _b.p[2] = __builtin_amdgcn_cvt_pkrtz(_e0, _e1);          \
            _b.p[3] = __builtin_amdgcn_cvt_pkrtz(_e2, _e3);          \
            f32x4 _zc = {0.f, 0.f, 0.f, 0.f};                        \
            f32x4 _acc = MFMA32((A1F), _b.v, _zc);                   \
            _acc = MFMA32((A2F), _b.v, _acc);                        \
            h0 = fmaxf(_acc.x, 0.f);                                 \
            h1 = fmaxf(_acc.y, 0.f);                                 \
            h2 = fmaxf(_acc.z, 0.f);                                 \
            h3 = biaslane ? 1.0f : fmaxf(_acc.w, 0.f);               \
        }
        HLAYER(A1_0, A2_0)
        HLAYER(A1_1, A2_1)
        HLAYER(A1_2, A2_2)
        HLAYER(A1_3, A2_3)
        HLAYER(A1_4, A2_4)
#undef HLAYER

        // final dot: partial over this lane's 4 rows (f32); wl3=0 for the
        // bias group so the injected 1.0 is harmless. Butterfly over the 4
        // lane groups, add bias, clip; lanes 0-15 store.
        float s = fmaf(wl0, h0, fmaf(wl1, h1, fmaf(wl2, h2, wl3 * h3)));
        s += __shfl_xor(s, 16, 64);
        s += __shfl_xor(s, 32, 64);
        const float y = fminf(fmaxf(s + bl0, 0.f), 1.f);
        if (lane < 16 && x < XOUT) orow[x] = y;
    }
}

extern "C" void kernel_launch(void* const* d_in, const int* in_sizes, int n_in,
                              void* d_out, int out_size, void* d_ws, size_t ws_size,
                              hipStream_t stream) {
    const float* rho = (const float*)d_in[0];
    const float* w0  = (const float*)d_in[1];
    const float* b0  = (const float*)d_in[2];
    const float* Wh  = (const float*)d_in[3];
    const float* bh  = (const float*)d_in[4];
    const float* Wl  = (const float*)d_in[5];
    const float* bl  = (const float*)d_in[6];
    float* out = (float*)d_out;

    dim3 grid(NBLOCKS);   // 8192 blocks x 4 waves x 16 tiles x 16 pos = 8.39M
    dim3 block(256);
    cnn_mfma_kernel<<<grid, block, 0, stream>>>(rho, w0, b0, Wh, bh, Wl, bl, out);
}

// Round 18
// 138.170 us; speedup vs baseline: 1.1059x; 1.1059x over previous
//
#include <hip/hip_runtime.h>

typedef __attribute__((ext_vector_type(8))) _Float16 half8;
typedef __attribute__((ext_vector_type(2))) __fp16 fp16x2;
typedef __attribute__((ext_vector_type(4))) float f32x4;

#define XDIM 8192
#define XOUT 8191
#define TPW 16                     // tiles (of 16 positions) per wave
#define NTILES (1024 * 512)        // 512 tiles per row, 1024 rows
#define NBLOCKS (NTILES / TPW / 4) // 4 waves per block

union H8 {
    fp16x2 p[4];
    half8 v;
};

#define MFMA32(A, B, C) __builtin_amdgcn_mfma_f32_16x16x32_f16((A), (B), (C), 0, 0, 0)

// ---------------------------------------------------------------------------
// Setup kernel: one wave precomputes, for each of the 64 lane roles, the
// PREPARED MFMA fragments (r17-verified math, bias folded into the k=15
// column) and packed fconv/Wl quads. ws layout:
//   half8  wsA[10*64]  : A1_L at [L*64+lane], A2_L at [(5+L)*64+lane]
//   float4 wsF[64*4]   : per lane {fw0}, {fw1}, {fb}, {wl}   (after 10240 B)
// Main kernel then "rebuilds" any fragment with ONE dwordx4 load (L1-hit)
// instead of the load+cvt+fma_mix+pack chain the allocator kept re-running
// per tile (the r9-r17 ~250 VALU inst/tile overhead).
// ---------------------------------------------------------------------------
__global__ __launch_bounds__(64) void cnn_prep_kernel(
    const float* __restrict__ w0, const float* __restrict__ b0,
    const float* __restrict__ Wh, const float* __restrict__ bh,
    const float* __restrict__ Wl, void* __restrict__ ws) {
    const int lane = threadIdx.x & 63;
    const int lm = lane & 15;
    const int kb = (lane >> 4) * 4;
    const bool biaslane = (kb == 12);

    half8* wsA = (half8*)ws;
    float4* wsF = (float4*)((char*)ws + 10240);

    for (int L = 0; L < 5; ++L) {
        float _w0 = (lm < 15) ? Wh[L*225 + lm*15 + kb + 0] : 0.f;
        float _w1 = (lm < 15) ? Wh[L*225 + lm*15 + kb + 1] : 0.f;
        float _w2 = (lm < 15) ? Wh[L*225 + lm*15 + kb + 2] : 0.f;
        float _w3 = (lm < 15) ? (biaslane ? bh[L*15 + lm]
                                          : Wh[L*225 + lm*15 + kb + 3]) : 0.f;
        fp16x2 h01 = __builtin_amdgcn_cvt_pkrtz(_w0, _w1);
        fp16x2 h23 = __builtin_amdgcn_cvt_pkrtz(_w2, _w3);
        const float e0 = fmaf(-1.0f, (float)h01.x, _w0);
        const float e1 = fmaf(-1.0f, (float)h01.y, _w1);
        const float e2 = fmaf(-1.0f, (float)h23.x, _w2);
        const float e3 = fmaf(-1.0f, (float)h23.y, _w3);
        fp16x2 l01 = __builtin_amdgcn_cvt_pkrtz(e0, e1);
        fp16x2 l23 = __builtin_amdgcn_cvt_pkrtz(e2, e3);
        H8 u1, u2;
        u1.p[0] = h01; u1.p[1] = h23; u1.p[2] = h01; u1.p[3] = h23;   // [Whi|Whi]
        fp16x2 z = __builtin_amdgcn_cvt_pkrtz(0.f, 0.f);
        u2.p[0] = l01; u2.p[1] = l23; u2.p[2] = z;   u2.p[3] = z;     // [Wlo|0]
        wsA[L*64 + lane] = u1.v;
        wsA[(5+L)*64 + lane] = u2.v;
    }

    float4 f0, f1, f2, f3;
    f0.x = (kb+0 < 15) ? w0[2*(kb+0)]   : 0.f;
    f0.y = (kb+1 < 15) ? w0[2*(kb+1)]   : 0.f;
    f0.z = (kb+2 < 15) ? w0[2*(kb+2)]   : 0.f;
    f0.w = (kb+3 < 15) ? w0[2*(kb+3)]   : 0.f;
    f1.x = (kb+0 < 15) ? w0[2*(kb+0)+1] : 0.f;
    f1.y = (kb+1 < 15) ? w0[2*(kb+1)+1] : 0.f;
    f1.z = (kb+2 < 15) ? w0[2*(kb+2)+1] : 0.f;
    f1.w = (kb+3 < 15) ? w0[2*(kb+3)+1] : 0.f;
    f2.x = (kb+0 < 15) ? b0[kb+0] : 0.f;
    f2.y = (kb+1 < 15) ? b0[kb+1] : 0.f;
    f2.z = (kb+2 < 15) ? b0[kb+2] : 0.f;
    f2.w = (kb+3 < 15) ? b0[kb+3] : 0.f;
    f3.x = (kb+0 < 15) ? Wl[kb+0] : 0.f;
    f3.y = (kb+1 < 15) ? Wl[kb+1] : 0.f;
    f3.z = (kb+2 < 15) ? Wl[kb+2] : 0.f;
    f3.w = (kb+3 < 15) ? Wl[kb+3] : 0.f;
    wsF[lane*4 + 0] = f0;
    wsF[lane*4 + 1] = f1;
    wsF[lane*4 + 2] = f2;
    wsF[lane*4 + 3] = f3;
}

__global__ __attribute__((amdgpu_flat_work_group_size(256, 256)))
void cnn_mfma_kernel(
    const float* __restrict__ rho, const float* __restrict__ bl,
    const void* __restrict__ ws, float* __restrict__ out) {
    const int lane = threadIdx.x & 63;
    const int lm = lane & 15;          // B-col (position) / D-col
    const int kb = (lane >> 4) * 4;    // k-base / D row-base
    const bool biaslane = (kb == 12);

    const half8* wsA = (const half8*)ws;
    const float4* wsF = (const float4*)((const char*)ws + 10240);

    // Prepared fragments: ONE dwordx4 each; if the allocator reloads these
    // per tile it costs a VMEM issue (L1-hit), not a 14-inst VALU chain.
    const half8 A1_0 = wsA[0*64 + lane];
    const half8 A1_1 = wsA[1*64 + lane];
    const half8 A1_2 = wsA[2*64 + lane];
    const half8 A1_3 = wsA[3*64 + lane];
    const half8 A1_4 = wsA[4*64 + lane];
    const half8 A2_0 = wsA[5*64 + lane];
    const half8 A2_1 = wsA[6*64 + lane];
    const half8 A2_2 = wsA[7*64 + lane];
    const half8 A2_3 = wsA[8*64 + lane];
    const half8 A2_4 = wsA[9*64 + lane];
    const float4 F0 = wsF[lane*4 + 0];   // fw0
    const float4 F1 = wsF[lane*4 + 1];   // fw1
    const float4 F2 = wsF[lane*4 + 2];   // fb
    const float4 F3 = wsF[lane*4 + 3];   // wl
    const float bl0 = bl[0];

    // ---- each wave owns 16 consecutive tiles of one row ----
    const int wid = blockIdx.x * 4 + (threadIdx.x >> 6);   // 0..32767
    const int brow = wid >> 5;                             // 32 waves per row
    const int xb = ((wid & 31) << 8) + lm;                 // + t*16
    const float* rrow = rho + (size_t)brow * XDIM;
    float* orow = out + (size_t)brow * XOUT;

#pragma unroll 2
    for (int t = 0; t < TPW; ++t) {
        const int x = xb + t * 16;                 // <= 8191
        const float r0 = rrow[x];
        const float r1 = rrow[(x < XDIM - 1) ? x + 1 : XDIM - 1];

        // first conv (k=2) + relu; bias-slot lane's elem3 carries 1.0
        float h0 = fmaxf(fmaf(F0.x, r0, fmaf(F1.x, r1, F2.x)), 0.f);
        float h1 = fmaxf(fmaf(F0.y, r0, fmaf(F1.y, r1, F2.y)), 0.f);
        float h2 = fmaxf(fmaf(F0.z, r0, fmaf(F1.z, r1, F2.z)), 0.f);
        float h3 = biaslane ? 1.0f
                            : fmaxf(fmaf(F0.w, r0, fmaf(F1.w, r1, F2.w)), 0.f);

        // Per layer: B = [hhi|hlo]; D = A1*B + A2*B (bias via k=15 slot).
#define HLAYER(A1F, A2F)                                             \
        {                                                            \
            H8 _b;                                                   \
            _b.p[0] = __builtin_amdgcn_cvt_pkrtz(h0, h1);            \
            _b.p[1] = __builtin_amdgcn_cvt_pkrtz(h2, h3);            \
            const float _e0 = fmaf(-1.0f, (float)_b.p[0].x, h0);     \
            const float _e1 = fmaf(-1.0f, (float)_b.p[0].y, h1);     \
            const float _e2 = fmaf(-1.0f, (float)_b.p[1].x, h2);     \
            const float _e3 = fmaf(-1.0f, (float)_b.p[1].y, h3);     \
            _b.p[2] = __builtin_amdgcn_cvt_pkrtz(_e0, _e1);          \
            _b.p[3] = __builtin_amdgcn_cvt_pkrtz(_e2, _e3);          \
            f32x4 _zc = {0.f, 0.f, 0.f, 0.f};                        \
            f32x4 _acc = MFMA32((A1F), _b.v, _zc);                   \
            _acc = MFMA32((A2F), _b.v, _acc);                        \
            h0 = fmaxf(_acc.x, 0.f);                                 \
            h1 = fmaxf(_acc.y, 0.f);                                 \
            h2 = fmaxf(_acc.z, 0.f);                                 \
            h3 = biaslane ? 1.0f : fmaxf(_acc.w, 0.f);               \
        }
        HLAYER(A1_0, A2_0)
        HLAYER(A1_1, A2_1)
        HLAYER(A1_2, A2_2)
        HLAYER(A1_3, A2_3)
        HLAYER(A1_4, A2_4)
#undef HLAYER

        // final dot (wl3 = 0 for the bias group) + butterfly + clip + store
        float s = fmaf(F3.x, h0, fmaf(F3.y, h1, fmaf(F3.z, h2, F3.w * h3)));
        s += __shfl_xor(s, 16, 64);
        s += __shfl_xor(s, 32, 64);
        const float y = fminf(fmaxf(s + bl0, 0.f), 1.f);
        if (lane < 16 && x < XOUT) orow[x] = y;
    }
}

extern "C" void kernel_launch(void* const* d_in, const int* in_sizes, int n_in,
                              void* d_out, int out_size, void* d_ws, size_t ws_size,
                              hipStream_t stream) {
    const float* rho = (const float*)d_in[0];
    const float* w0  = (const float*)d_in[1];
    const float* b0  = (const float*)d_in[2];
    const float* Wh  = (const float*)d_in[3];
    const float* bh  = (const float*)d_in[4];
    const float* Wl  = (const float*)d_in[5];
    const float* bl  = (const float*)d_in[6];
    float* out = (float*)d_out;

    cnn_prep_kernel<<<1, 64, 0, stream>>>(w0, b0, Wh, bh, Wl, d_ws);
    cnn_mfma_kernel<<<NBLOCKS, 256, 0, stream>>>(rho, bl, d_ws, out);
}